// Round 2
// baseline (37.831 us; speedup 1.0000x reference)
//
#include <hip/hip_runtime.h>
#include <stdint.h>
#include <math.h>

#define NUM_TOKENS 16384
#define NUM_EXPERTS 64
#define TOP_K 8

__device__ __forceinline__ uint32_t rotl32(uint32_t v, int s) {
  return (v << s) | (v >> (32 - s));
}

// Threefry-2x32, 20 rounds, key (0,42) -> JAX jax.random.key(42).
// Partitionable-mode 32-bit draw for flat index j: counter (0, j), return o0 ^ o1.
__device__ __forceinline__ uint32_t threefry_bits(uint32_t c0, uint32_t c1) {
  const uint32_t k0 = 0u, k1 = 42u;
  const uint32_t k2 = k0 ^ k1 ^ 0x1BD11BDAu;
  uint32_t x0 = c0 + k0, x1 = c1 + k1;
#define TF_R(r) { x0 += x1; x1 = rotl32(x1, (r)); x1 ^= x0; }
  TF_R(13) TF_R(15) TF_R(26) TF_R(6)  x0 += k1; x1 += k2 + 1u;
  TF_R(17) TF_R(29) TF_R(16) TF_R(24) x0 += k2; x1 += k0 + 2u;
  TF_R(13) TF_R(15) TF_R(26) TF_R(6)  x0 += k0; x1 += k1 + 3u;
  TF_R(17) TF_R(29) TF_R(16) TF_R(24) x0 += k1; x1 += k2 + 4u;
  TF_R(13) TF_R(15) TF_R(26) TF_R(6)  x0 += k2; x1 += k0 + 5u;
#undef TF_R
  return x0 ^ x1;
}

// XLA CHLO erfinv f32 (Giles polynomial), with XLA EmitLog1p semantics.
// No FP contraction: XLA emits unfused fmul/fadd.
__device__ __forceinline__ float xla_erfinv_f32(float x) {
#pragma clang fp contract(off)
  float s = x * x;          // x*x, exact IEEE mul
  float nx = -s;            // -x*x
  float l1p;
  if (__builtin_fabsf(nx) < 1e-4f) {
    // EmitLog1p small branch: ((-0.5*x) + 1) * x
    l1p = ((-0.5f * nx) + 1.0f) * nx;
  } else {
    float t = nx + 1.0f;
    // emulate correctly-rounded glibc logf via double log (OCML f64)
    l1p = (float)log((double)t);
  }
  float w = -l1p;
  float p;
  if (w < 5.0f) {
    float h = w - 2.5f;
    p = 2.81022636e-08f;
    p = 3.43273939e-07f  + p * h;
    p = -3.5233877e-06f  + p * h;
    p = -4.39150654e-06f + p * h;
    p = 0.00021858087f   + p * h;
    p = -0.00125372503f  + p * h;
    p = -0.00417768164f  + p * h;
    p = 0.246640727f     + p * h;
    p = 1.50140941f      + p * h;
  } else {
    float h = __builtin_sqrtf(w) - 3.0f;
    p = -0.000200214257f;
    p = 0.000100950558f  + p * h;
    p = 0.00134934322f   + p * h;
    p = -0.00367342844f  + p * h;
    p = 0.00573950773f   + p * h;
    p = -0.0076224613f   + p * h;
    p = 0.00943887047f   + p * h;
    p = 1.00167406f      + p * h;
    p = 2.83297682f      + p * h;
  }
  return p * x;
}

// One wave (64 lanes) per token; lane = expert id.
__global__ __launch_bounds__(256) void router_kernel(
    const float* __restrict__ bias, float* __restrict__ out) {
#pragma clang fp contract(off)
  __shared__ float sel[4][TOP_K];
  const int wv   = threadIdx.x >> 6;
  const int lane = threadIdx.x & 63;
  const int t    = blockIdx.x * 4 + wv;
  const uint32_t j = (uint32_t)t * 64u + (uint32_t)lane;

  // --- rnd = jax.random.normal(key(42)) element j ---
  uint32_t bits = threefry_bits(0u, j);
  float f = __uint_as_float((bits >> 9) | 0x3F800000u) - 1.0f;  // [0,1), exact
  const float LO = __uint_as_float(0xBF7FFFFFu);                // nextafter(-1,0)
  float u = (f * 2.0f) + LO;   // f*2 exact; maxval-minval rounds to 2.0f
  u = fmaxf(LO, u);
  float er = xla_erfinv_f32(u);
  float n = __uint_as_float(0x3FB504F3u) * er;                  // f32(sqrt(2)) * erfinv

  // --- sigmoid via XLA LogisticExpander: 1/(1+exp(-x)) ---
  float efl = (float)exp(-(double)n);                           // CR expf emulation
  float score = 1.0f / (1.0f + efl);                            // HIP f32 div is CR
  float adj = score + bias[lane];                               // selection key

  // --- stable descending rank across the wave (jax.lax.top_k tie: lower idx first) ---
  int rank = 0;
#pragma unroll
  for (int d = 1; d < 64; ++d) {
    int o = (lane + d) & 63;
    float ov = __shfl(adj, o, 64);
    rank += (ov > adj || (ov == adj && o < lane)) ? 1 : 0;
  }

  if (rank < TOP_K) sel[wv][rank] = score;
  __syncthreads();

  // sequential sum over the 8 selected scores (rank order), like jnp.sum
  float sum = 0.0f;
#pragma unroll
  for (int k = 0; k < TOP_K; ++k) sum = sum + sel[wv][k];
  float denom = sum + 1e-20f;

  if (rank < TOP_K) {
    float v = (score / denom) * 2.5f;
    out[t * TOP_K + rank] = v;                                   // top_scores
    out[NUM_TOKENS * TOP_K + t * TOP_K + rank] = (float)lane;    // indices (as f32)
  }
}

// Single-block histogram over the 131072 selected indices.
__global__ __launch_bounds__(1024) void hist_kernel(
    const float* __restrict__ idx, float* __restrict__ hist) {
  __shared__ unsigned int h[NUM_EXPERTS];
  if (threadIdx.x < NUM_EXPERTS) h[threadIdx.x] = 0u;
  __syncthreads();
  const int n4 = (NUM_TOKENS * TOP_K) / 4;
  const float4* idx4 = (const float4*)idx;
  for (int i = threadIdx.x; i < n4; i += 1024) {
    float4 v = idx4[i];
    atomicAdd(&h[(int)v.x], 1u);
    atomicAdd(&h[(int)v.y], 1u);
    atomicAdd(&h[(int)v.z], 1u);
    atomicAdd(&h[(int)v.w], 1u);
  }
  __syncthreads();
  if (threadIdx.x < NUM_EXPERTS) hist[threadIdx.x] = (float)h[threadIdx.x];
}

extern "C" void kernel_launch(void* const* d_in, const int* in_sizes, int n_in,
                              void* d_out, int out_size, void* d_ws, size_t ws_size,
                              hipStream_t stream) {
  (void)in_sizes; (void)n_in; (void)d_ws; (void)ws_size; (void)out_size;
  // Forward output is independent of x (d_in[0]) and gate_w (d_in[1]):
  // RandomSTE replaces logits with fresh normals in the forward pass.
  const float* bias = (const float*)d_in[2];
  float* out = (float*)d_out;
  float* idx_region = out + NUM_TOKENS * TOP_K;
  float* hist = out + 2 * NUM_TOKENS * TOP_K;

  router_kernel<<<NUM_TOKENS / 4, 256, 0, stream>>>(bias, out);
  hist_kernel<<<1, 1024, 0, stream>>>(idx_region, hist);
}

// Round 3
// 34.657 us; speedup vs baseline: 1.0916x; 1.0916x over previous
//
#include <hip/hip_runtime.h>
#include <stdint.h>
#include <math.h>

#define NUM_TOKENS 16384
#define NUM_EXPERTS 64
#define TOP_K 8

__device__ __forceinline__ uint32_t rotl32(uint32_t v, int s) {
  return (v << s) | (v >> (32 - s));
}

// Threefry-2x32, 20 rounds, key (0,42) -> JAX jax.random.key(42).
// Partitionable-mode 32-bit draw for flat index j: counter (0, j), return o0 ^ o1.
__device__ __forceinline__ uint32_t threefry_bits(uint32_t c0, uint32_t c1) {
  const uint32_t k0 = 0u, k1 = 42u;
  const uint32_t k2 = k0 ^ k1 ^ 0x1BD11BDAu;
  uint32_t x0 = c0 + k0, x1 = c1 + k1;
#define TF_R(r) { x0 += x1; x1 = rotl32(x1, (r)); x1 ^= x0; }
  TF_R(13) TF_R(15) TF_R(26) TF_R(6)  x0 += k1; x1 += k2 + 1u;
  TF_R(17) TF_R(29) TF_R(16) TF_R(24) x0 += k2; x1 += k0 + 2u;
  TF_R(13) TF_R(15) TF_R(26) TF_R(6)  x0 += k0; x1 += k1 + 3u;
  TF_R(17) TF_R(29) TF_R(16) TF_R(24) x0 += k1; x1 += k2 + 4u;
  TF_R(13) TF_R(15) TF_R(26) TF_R(6)  x0 += k2; x1 += k0 + 5u;
#undef TF_R
  return x0 ^ x1;
}

// XLA CHLO erfinv f32 (Giles polynomial), with XLA EmitLog1p semantics.
// No FP contraction: XLA emits unfused fmul/fadd.
__device__ __forceinline__ float xla_erfinv_f32(float x) {
#pragma clang fp contract(off)
  float s = x * x;          // x*x, exact IEEE mul
  float nx = -s;            // -x*x
  float l1p;
  if (__builtin_fabsf(nx) < 1e-4f) {
    // EmitLog1p small branch: ((-0.5*x) + 1) * x
    l1p = ((-0.5f * nx) + 1.0f) * nx;
  } else {
    float t = nx + 1.0f;
    // emulate correctly-rounded glibc logf via double log (OCML f64)
    l1p = (float)log((double)t);
  }
  float w = -l1p;
  float p;
  if (w < 5.0f) {
    float h = w - 2.5f;
    p = 2.81022636e-08f;
    p = 3.43273939e-07f  + p * h;
    p = -3.5233877e-06f  + p * h;
    p = -4.39150654e-06f + p * h;
    p = 0.00021858087f   + p * h;
    p = -0.00125372503f  + p * h;
    p = -0.00417768164f  + p * h;
    p = 0.246640727f     + p * h;
    p = 1.50140941f      + p * h;
  } else {
    float h = __builtin_sqrtf(w) - 3.0f;
    p = -0.000200214257f;
    p = 0.000100950558f  + p * h;
    p = 0.00134934322f   + p * h;
    p = -0.00367342844f  + p * h;
    p = 0.00573950773f   + p * h;
    p = -0.0076224613f   + p * h;
    p = 0.00943887047f   + p * h;
    p = 1.00167406f      + p * h;
    p = 2.83297682f      + p * h;
  }
  return p * x;
}

// One wave (64 lanes) per token; lane = expert id. (verified bit-exact path — unchanged)
__global__ __launch_bounds__(256) void router_kernel(
    const float* __restrict__ bias, float* __restrict__ out) {
#pragma clang fp contract(off)
  __shared__ float sel[4][TOP_K];
  const int wv   = threadIdx.x >> 6;
  const int lane = threadIdx.x & 63;
  const int t    = blockIdx.x * 4 + wv;
  const uint32_t j = (uint32_t)t * 64u + (uint32_t)lane;

  // --- rnd = jax.random.normal(key(42)) element j ---
  uint32_t bits = threefry_bits(0u, j);
  float f = __uint_as_float((bits >> 9) | 0x3F800000u) - 1.0f;  // [0,1), exact
  const float LO = __uint_as_float(0xBF7FFFFFu);                // nextafter(-1,0)
  float u = (f * 2.0f) + LO;   // f*2 exact; maxval-minval rounds to 2.0f
  u = fmaxf(LO, u);
  float er = xla_erfinv_f32(u);
  float n = __uint_as_float(0x3FB504F3u) * er;                  // f32(sqrt(2)) * erfinv

  // --- sigmoid via XLA LogisticExpander: 1/(1+exp(-x)) ---
  float efl = (float)exp(-(double)n);                           // CR expf emulation
  float score = 1.0f / (1.0f + efl);                            // HIP f32 div is CR
  float adj = score + bias[lane];                               // selection key

  // --- stable descending rank across the wave (jax.lax.top_k tie: lower idx first) ---
  int rank = 0;
#pragma unroll
  for (int d = 1; d < 64; ++d) {
    int o = (lane + d) & 63;
    float ov = __shfl(adj, o, 64);
    rank += (ov > adj || (ov == adj && o < lane)) ? 1 : 0;
  }

  if (rank < TOP_K) sel[wv][rank] = score;
  __syncthreads();

  // sequential sum over the 8 selected scores (rank order), like jnp.sum
  float sum = 0.0f;
#pragma unroll
  for (int k = 0; k < TOP_K; ++k) sum = sum + sel[wv][k];
  float denom = sum + 1e-20f;

  if (rank < TOP_K) {
    float v = (score / denom) * 2.5f;
    out[t * TOP_K + rank] = v;                                   // top_scores
    out[NUM_TOKENS * TOP_K + t * TOP_K + rank] = (float)lane;    // indices (as f32)
  }
}

// Parallel histogram: 128 blocks, per-block LDS partials, then 8192 global
// f32 atomicAdds to 64 addresses (hist region pre-zeroed via hipMemsetAsync).
#define HIST_BLOCKS 128
__global__ __launch_bounds__(256) void hist_kernel(
    const float* __restrict__ idx, float* __restrict__ hist) {
  __shared__ unsigned int h[NUM_EXPERTS];
  if (threadIdx.x < NUM_EXPERTS) h[threadIdx.x] = 0u;
  __syncthreads();
  const int n4 = (NUM_TOKENS * TOP_K) / 4;          // 32768 float4s
  const float4* idx4 = (const float4*)idx;
  for (int i = blockIdx.x * 256 + threadIdx.x; i < n4; i += HIST_BLOCKS * 256) {
    float4 v = idx4[i];
    atomicAdd(&h[(int)v.x], 1u);
    atomicAdd(&h[(int)v.y], 1u);
    atomicAdd(&h[(int)v.z], 1u);
    atomicAdd(&h[(int)v.w], 1u);
  }
  __syncthreads();
  if (threadIdx.x < NUM_EXPERTS) {
    unsigned int c = h[threadIdx.x];
    if (c) atomicAdd(&hist[threadIdx.x], (float)c);  // exact: integer sums < 2^24
  }
}

extern "C" void kernel_launch(void* const* d_in, const int* in_sizes, int n_in,
                              void* d_out, int out_size, void* d_ws, size_t ws_size,
                              hipStream_t stream) {
  (void)in_sizes; (void)n_in; (void)d_ws; (void)ws_size; (void)out_size;
  // Forward output is independent of x (d_in[0]) and gate_w (d_in[1]):
  // RandomSTE replaces logits with fresh normals in the forward pass.
  const float* bias = (const float*)d_in[2];
  float* out = (float*)d_out;
  float* idx_region = out + NUM_TOKENS * TOP_K;
  float* hist = out + 2 * NUM_TOKENS * TOP_K;

  hipMemsetAsync(hist, 0, NUM_EXPERTS * sizeof(float), stream);
  router_kernel<<<NUM_TOKENS / 4, 256, 0, stream>>>(bias, out);
  hist_kernel<<<HIST_BLOCKS, 256, 0, stream>>>(idx_region, hist);
}

// Round 4
// 24.166 us; speedup vs baseline: 1.5655x; 1.4341x over previous
//
#include <hip/hip_runtime.h>
#include <stdint.h>
#include <math.h>

#define NUM_TOKENS 16384
#define NUM_EXPERTS 64
#define TOP_K 8

__device__ __forceinline__ uint32_t rotl32(uint32_t v, int s) {
  return (v << s) | (v >> (32 - s));
}

// Threefry-2x32, 20 rounds, key (0,42) -> JAX jax.random.key(42).
// Partitionable-mode 32-bit draw for flat index j: counter (0, j), return o0 ^ o1.
__device__ __forceinline__ uint32_t threefry_bits(uint32_t c0, uint32_t c1) {
  const uint32_t k0 = 0u, k1 = 42u;
  const uint32_t k2 = k0 ^ k1 ^ 0x1BD11BDAu;
  uint32_t x0 = c0 + k0, x1 = c1 + k1;
#define TF_R(r) { x0 += x1; x1 = rotl32(x1, (r)); x1 ^= x0; }
  TF_R(13) TF_R(15) TF_R(26) TF_R(6)  x0 += k1; x1 += k2 + 1u;
  TF_R(17) TF_R(29) TF_R(16) TF_R(24) x0 += k2; x1 += k0 + 2u;
  TF_R(13) TF_R(15) TF_R(26) TF_R(6)  x0 += k0; x1 += k1 + 3u;
  TF_R(17) TF_R(29) TF_R(16) TF_R(24) x0 += k1; x1 += k2 + 4u;
  TF_R(13) TF_R(15) TF_R(26) TF_R(6)  x0 += k2; x1 += k0 + 5u;
#undef TF_R
  return x0 ^ x1;
}

// XLA CHLO erfinv f32 (Giles polynomial), with XLA EmitLog1p semantics.
// No FP contraction: XLA emits unfused fmul/fadd.
__device__ __forceinline__ float xla_erfinv_f32(float x) {
#pragma clang fp contract(off)
  float s = x * x;          // x*x, exact IEEE mul
  float nx = -s;            // -x*x
  float l1p;
  if (__builtin_fabsf(nx) < 1e-4f) {
    // EmitLog1p small branch: ((-0.5*x) + 1) * x
    l1p = ((-0.5f * nx) + 1.0f) * nx;
  } else {
    float t = nx + 1.0f;
    // emulate correctly-rounded glibc logf via double log (OCML f64)
    l1p = (float)log((double)t);
  }
  float w = -l1p;
  float p;
  if (w < 5.0f) {
    float h = w - 2.5f;
    p = 2.81022636e-08f;
    p = 3.43273939e-07f  + p * h;
    p = -3.5233877e-06f  + p * h;
    p = -4.39150654e-06f + p * h;
    p = 0.00021858087f   + p * h;
    p = -0.00125372503f  + p * h;
    p = -0.00417768164f  + p * h;
    p = 0.246640727f     + p * h;
    p = 1.50140941f      + p * h;
  } else {
    float h = __builtin_sqrtf(w) - 3.0f;
    p = -0.000200214257f;
    p = 0.000100950558f  + p * h;
    p = 0.00134934322f   + p * h;
    p = -0.00367342844f  + p * h;
    p = 0.00573950773f   + p * h;
    p = -0.0076224613f   + p * h;
    p = 0.00943887047f   + p * h;
    p = 1.00167406f      + p * h;
    p = 2.83297682f      + p * h;
  }
  return p * x;
}

// One wave (64 lanes) per token; lane = expert id. Math path unchanged
// (bit-exact verified R2); ranking now via LDS broadcast reads instead of
// 63 serial ds_bpermute shuffles.
__global__ __launch_bounds__(256) void router_kernel(
    const float* __restrict__ bias, float* __restrict__ out,
    float* __restrict__ hist) {
#pragma clang fp contract(off)
  __shared__ float adjbuf[4][64];
  __shared__ float sel[4][TOP_K];
  const int wv   = threadIdx.x >> 6;
  const int lane = threadIdx.x & 63;
  const int t    = blockIdx.x * 4 + wv;

  // zero the hist region (replaces the hipMemsetAsync graph node); no other
  // router block touches hist, and hist_kernel runs in the next dispatch.
  if (blockIdx.x == 0 && threadIdx.x < NUM_EXPERTS) hist[threadIdx.x] = 0.0f;

  const uint32_t j = (uint32_t)t * 64u + (uint32_t)lane;

  // --- rnd = jax.random.normal(key(42)) element j ---
  uint32_t bits = threefry_bits(0u, j);
  float f = __uint_as_float((bits >> 9) | 0x3F800000u) - 1.0f;  // [0,1), exact
  const float LO = __uint_as_float(0xBF7FFFFFu);                // nextafter(-1,0)
  float u = (f * 2.0f) + LO;   // f*2 exact; maxval-minval rounds to 2.0f
  u = fmaxf(LO, u);
  float er = xla_erfinv_f32(u);
  float n = __uint_as_float(0x3FB504F3u) * er;                  // f32(sqrt(2)) * erfinv

  // --- sigmoid via XLA LogisticExpander: 1/(1+exp(-x)) ---
  float efl = (float)exp(-(double)n);                           // CR expf emulation
  float score = 1.0f / (1.0f + efl);                            // HIP f32 div is CR
  float adj = score + bias[lane];                               // selection key

  // --- stable descending rank: all-pairs compare via LDS broadcast reads ---
  adjbuf[wv][lane] = adj;
  __syncthreads();

  int rank = 0;
  const float4* ab = (const float4*)(&adjbuf[wv][0]);
#pragma unroll
  for (int i = 0; i < 16; ++i) {
    float4 v = ab[i];   // same address across all 64 lanes -> LDS broadcast
    const int b = 4 * i;
    // self-compare (j==lane) contributes 0: v==adj but j<lane is false.
    rank += (v.x > adj || (v.x == adj && (b + 0) < lane)) ? 1 : 0;
    rank += (v.y > adj || (v.y == adj && (b + 1) < lane)) ? 1 : 0;
    rank += (v.z > adj || (v.z == adj && (b + 2) < lane)) ? 1 : 0;
    rank += (v.w > adj || (v.w == adj && (b + 3) < lane)) ? 1 : 0;
  }

  if (rank < TOP_K) sel[wv][rank] = score;
  __syncthreads();

  // sequential sum over the 8 selected scores (rank order), like jnp.sum
  float sum = 0.0f;
#pragma unroll
  for (int k = 0; k < TOP_K; ++k) sum = sum + sel[wv][k];
  float denom = sum + 1e-20f;

  if (rank < TOP_K) {
    float v = (score / denom) * 2.5f;
    out[t * TOP_K + rank] = v;                                   // top_scores
    out[NUM_TOKENS * TOP_K + t * TOP_K + rank] = (float)lane;    // indices (as f32)
  }
}

// Parallel histogram: 128 blocks, per-block LDS partials, then 8192 global
// f32 atomicAdds to 64 addresses (hist region zeroed by router block 0).
#define HIST_BLOCKS 128
__global__ __launch_bounds__(256) void hist_kernel(
    const float* __restrict__ idx, float* __restrict__ hist) {
  __shared__ unsigned int h[NUM_EXPERTS];
  if (threadIdx.x < NUM_EXPERTS) h[threadIdx.x] = 0u;
  __syncthreads();
  const int n4 = (NUM_TOKENS * TOP_K) / 4;          // 32768 float4s
  const float4* idx4 = (const float4*)idx;
  for (int i = blockIdx.x * 256 + threadIdx.x; i < n4; i += HIST_BLOCKS * 256) {
    float4 v = idx4[i];
    atomicAdd(&h[(int)v.x], 1u);
    atomicAdd(&h[(int)v.y], 1u);
    atomicAdd(&h[(int)v.z], 1u);
    atomicAdd(&h[(int)v.w], 1u);
  }
  __syncthreads();
  if (threadIdx.x < NUM_EXPERTS) {
    unsigned int c = h[threadIdx.x];
    if (c) atomicAdd(&hist[threadIdx.x], (float)c);  // exact: integer sums < 2^24
  }
}

extern "C" void kernel_launch(void* const* d_in, const int* in_sizes, int n_in,
                              void* d_out, int out_size, void* d_ws, size_t ws_size,
                              hipStream_t stream) {
  (void)in_sizes; (void)n_in; (void)d_ws; (void)ws_size; (void)out_size;
  // Forward output is independent of x (d_in[0]) and gate_w (d_in[1]):
  // RandomSTE replaces logits with fresh normals in the forward pass.
  const float* bias = (const float*)d_in[2];
  float* out = (float*)d_out;
  float* idx_region = out + NUM_TOKENS * TOP_K;
  float* hist = out + 2 * NUM_TOKENS * TOP_K;

  router_kernel<<<NUM_TOKENS / 4, 256, 0, stream>>>(bias, out, hist);
  hist_kernel<<<HIST_BLOCKS, 256, 0, stream>>>(idx_region, hist);
}